// Round 2
// baseline (360.092 us; speedup 1.0000x reference)
//
#include <hip/hip_runtime.h>
#include <math.h>

// LabelSmoothing KLDiv(sum) closed form.
// Per row r with t=target[r]:
//   t==0 (PAD): 0
//   else: C0 - CONF*x[t] - SV*(rowsum - x[0] - x[t])
//   C0 = CONF*log(CONF) + (V-2)*SV*log(SV),  SV = 0.1/(V-2)
// => streaming row-sum (memory-bound, ~262 MB f32) + 2 gathers per row.

#define LS_V 32000
#define LS_VEC (LS_V / 4)        // 8000 float4 per row
#define LS_BLOCK 256

__global__ __launch_bounds__(LS_BLOCK) void ls_rowloss_kernel(
    const float* __restrict__ x,
    const int* __restrict__ target,
    float* __restrict__ out)
{
    const int row = blockIdx.x;
    const int tid = threadIdx.x;
    const float4* __restrict__ xr =
        reinterpret_cast<const float4*>(x + (size_t)row * LS_V);

    // Coalesced vectorized row sum: lane i reads float4 #(i, i+256, ...).
    // Two independent accumulator chains to halve FADD dependency depth.
    float s0 = 0.0f, s1 = 0.0f;
#pragma unroll 4
    for (int i = tid; i < LS_VEC; i += 2 * LS_BLOCK) {
        float4 a = xr[i];
        s0 += (a.x + a.y) + (a.z + a.w);
        int j = i + LS_BLOCK;
        if (j < LS_VEC) {
            float4 b = xr[j];
            s1 += (b.x + b.y) + (b.z + b.w);
        }
    }
    float sum = s0 + s1;

    // wave-64 shuffle reduce
#pragma unroll
    for (int off = 32; off >= 1; off >>= 1)
        sum += __shfl_down(sum, off, 64);

    __shared__ float wsum[LS_BLOCK / 64];
    const int lane = tid & 63;
    const int wid  = tid >> 6;
    if (lane == 0) wsum[wid] = sum;
    __syncthreads();

    if (tid == 0) {
        float rowsum = (wsum[0] + wsum[1]) + (wsum[2] + wsum[3]);
        const int t = target[row];
        if (t != 0) {
            const float* __restrict__ xrow = x + (size_t)row * LS_V;
            const float xt = xrow[t];
            const float x0 = xrow[0];
            const float CONF = 0.9f;
            const float SV = 0.1f / 31998.0f;               // smoothing/(V-2)
            const float C0 = CONF * logf(CONF) + 31998.0f * SV * logf(SV);
            const float loss = C0 - CONF * xt - SV * ((rowsum - x0) - xt);
            atomicAdd(out, loss);   // device-scope by default (G12)
        }
    }
}

extern "C" void kernel_launch(void* const* d_in, const int* in_sizes, int n_in,
                              void* d_out, int out_size, void* d_ws, size_t ws_size,
                              hipStream_t stream) {
    const float* x      = (const float*)d_in[0];
    const int*   target = (const int*)d_in[1];
    float*       out    = (float*)d_out;

    const int n_rows = in_sizes[1];          // B*S = 2048

    hipMemsetAsync(out, 0, sizeof(float), stream);   // d_out is poisoned 0xAA
    ls_rowloss_kernel<<<n_rows, LS_BLOCK, 0, stream>>>(x, target, out);
}

// Round 3
// 356.473 us; speedup vs baseline: 1.0102x; 1.0102x over previous
//
#include <hip/hip_runtime.h>
#include <math.h>

// LabelSmoothing KLDiv(sum) closed form.
// Per row r with t=target[r]:
//   t==0 (PAD): 0
//   else: C0 - CONF*x[t] - SV*(rowsum - x[0] - x[t])
//   C0 = CONF*log(CONF) + (V-2)*SV*log(SV),  SV = 0.1/(V-2)
// => streaming row-sum (memory-bound, ~262 MB f32) + 2 gathers per row.
//
// R3: two-kernel structure. NO hipMemsetAsync in the graph — R2 showed the
// 4-byte fill dispatch cost ~159 us in replay (serialized against re-poison
// traffic). Kernel 1 writes per-row partials to d_ws unconditionally;
// kernel 2 reduces them and overwrites d_out (no init required).

#define LS_V 32000
#define LS_VEC (LS_V / 4)        // 8000 float4 per row
#define LS_BLOCK 256
#define LS_ROWS 2048             // B*S

__global__ __launch_bounds__(LS_BLOCK) void ls_rowloss_kernel(
    const float* __restrict__ x,
    const int* __restrict__ target,
    float* __restrict__ partial)   // [LS_ROWS] in d_ws
{
    const int row = blockIdx.x;
    const int tid = threadIdx.x;
    const float4* __restrict__ xr =
        reinterpret_cast<const float4*>(x + (size_t)row * LS_V);

    // Coalesced vectorized row sum: lane i reads float4 #(i, i+256, ...).
    // Two independent accumulator chains to halve FADD dependency depth.
    float s0 = 0.0f, s1 = 0.0f;
#pragma unroll 4
    for (int i = tid; i < LS_VEC; i += 2 * LS_BLOCK) {
        float4 a = xr[i];
        s0 += (a.x + a.y) + (a.z + a.w);
        int j = i + LS_BLOCK;
        if (j < LS_VEC) {
            float4 b = xr[j];
            s1 += (b.x + b.y) + (b.z + b.w);
        }
    }
    float sum = s0 + s1;

    // wave-64 shuffle reduce
#pragma unroll
    for (int off = 32; off >= 1; off >>= 1)
        sum += __shfl_down(sum, off, 64);

    __shared__ float wsum[LS_BLOCK / 64];
    const int lane = tid & 63;
    const int wid  = tid >> 6;
    if (lane == 0) wsum[wid] = sum;
    __syncthreads();

    if (tid == 0) {
        float rowsum = (wsum[0] + wsum[1]) + (wsum[2] + wsum[3]);
        const int t = target[row];
        float loss = 0.0f;                       // PAD rows contribute 0
        if (t != 0) {
            const float* __restrict__ xrow = x + (size_t)row * LS_V;
            const float xt = xrow[t];
            const float x0 = xrow[0];
            const float CONF = 0.9f;
            const float SV = 0.1f / 31998.0f;               // smoothing/(V-2)
            const float C0 = CONF * logf(CONF) + 31998.0f * SV * logf(SV);
            loss = C0 - CONF * xt - SV * ((rowsum - x0) - xt);
        }
        partial[row] = loss;   // unconditional write: d_ws is poisoned 0xAA
    }
}

__global__ __launch_bounds__(LS_BLOCK) void ls_finalize_kernel(
    const float* __restrict__ partial,
    float* __restrict__ out)
{
    const int tid = threadIdx.x;
    float sum = 0.0f;
#pragma unroll
    for (int i = tid; i < LS_ROWS; i += LS_BLOCK)
        sum += partial[i];

#pragma unroll
    for (int off = 32; off >= 1; off >>= 1)
        sum += __shfl_down(sum, off, 64);

    __shared__ float wsum[LS_BLOCK / 64];
    const int lane = tid & 63;
    const int wid  = tid >> 6;
    if (lane == 0) wsum[wid] = sum;
    __syncthreads();

    if (tid == 0)
        out[0] = (wsum[0] + wsum[1]) + (wsum[2] + wsum[3]);  // overwrite: no init needed
}

extern "C" void kernel_launch(void* const* d_in, const int* in_sizes, int n_in,
                              void* d_out, int out_size, void* d_ws, size_t ws_size,
                              hipStream_t stream) {
    const float* x      = (const float*)d_in[0];
    const int*   target = (const int*)d_in[1];
    float*       out    = (float*)d_out;
    float*       ws     = (float*)d_ws;

    const int n_rows = in_sizes[1];          // B*S = 2048

    ls_rowloss_kernel<<<n_rows, LS_BLOCK, 0, stream>>>(x, target, ws);
    ls_finalize_kernel<<<1, LS_BLOCK, 0, stream>>>(ws, out);
}

// Round 4
// 356.385 us; speedup vs baseline: 1.0104x; 1.0002x over previous
//
#include <hip/hip_runtime.h>
#include <math.h>

// LabelSmoothing KLDiv(sum) closed form.
// Per row r with t=target[r]:
//   t==0 (PAD): 0
//   else: C0 - CONF*x[t] - SV*(rowsum - x[0] - x[t])
//   C0 = CONF*log(CONF) + (V-2)*SV*log(SV),  SV = 0.1/(V-2)
// => streaming row-sum (memory-bound, ~262 MB f32) + 2 gathers per row.
//
// R4: micro-tuned A/B to pin the harness floor. R2 vs R3 showed the measured
// window is dominated by harness reset dispatches (1.049 GB d_ws fill @158us,
// d_in restore ~74us) that no kernel change can touch. This version:
//  - branch-free main loop (8000 = 31*256 + 64: 31 full strided iterations,
//    64-thread tail), 4 independent accumulator chains
//  - early gather of x[t], x[0] so the dependent load hides under the stream
// If dur_us is unchanged (~356), the kernel portion is at the memory roofline.

#define LS_V 32000
#define LS_VEC (LS_V / 4)        // 8000 float4 per row
#define LS_BLOCK 256
#define LS_FULL_ITERS 31         // 31*256 = 7936 float4; tail = 64
#define LS_ROWS 2048             // B*S

__global__ __launch_bounds__(LS_BLOCK) void ls_rowloss_kernel(
    const float* __restrict__ x,
    const int* __restrict__ target,
    float* __restrict__ partial)   // [LS_ROWS] in d_ws
{
    const int row = blockIdx.x;
    const int tid = threadIdx.x;
    const float* __restrict__ xrow = x + (size_t)row * LS_V;
    const float4* __restrict__ xr  = reinterpret_cast<const float4*>(xrow);

    // Early gather (thread 0 only): cold-miss latency hides under the stream.
    const int t = target[row];
    float xt = 0.0f, x0 = 0.0f;
    if (tid == 0 && t != 0) {
        xt = xrow[t];
        x0 = xrow[0];
    }

    // Branch-free coalesced row sum, 4 independent FADD chains.
    float s0 = 0.0f, s1 = 0.0f, s2 = 0.0f, s3 = 0.0f;
#pragma unroll 4
    for (int k = 0; k < LS_FULL_ITERS; ++k) {
        float4 v = xr[tid + k * LS_BLOCK];
        s0 += v.x; s1 += v.y; s2 += v.z; s3 += v.w;
    }
    if (tid < LS_VEC - LS_FULL_ITERS * LS_BLOCK) {      // 64-thread tail
        float4 v = xr[LS_FULL_ITERS * LS_BLOCK + tid];
        s0 += v.x; s1 += v.y; s2 += v.z; s3 += v.w;
    }
    float sum = (s0 + s1) + (s2 + s3);

    // wave-64 shuffle reduce
#pragma unroll
    for (int off = 32; off >= 1; off >>= 1)
        sum += __shfl_down(sum, off, 64);

    __shared__ float wsum[LS_BLOCK / 64];
    const int lane = tid & 63;
    const int wid  = tid >> 6;
    if (lane == 0) wsum[wid] = sum;
    __syncthreads();

    if (tid == 0) {
        float rowsum = (wsum[0] + wsum[1]) + (wsum[2] + wsum[3]);
        float loss = 0.0f;                       // PAD rows contribute 0
        if (t != 0) {
            const float CONF = 0.9f;
            const float SV = 0.1f / 31998.0f;               // smoothing/(V-2)
            const float C0 = CONF * logf(CONF) + 31998.0f * SV * logf(SV);
            loss = C0 - CONF * xt - SV * ((rowsum - x0) - xt);
        }
        partial[row] = loss;   // unconditional write: d_ws is poisoned 0xAA
    }
}

__global__ __launch_bounds__(LS_BLOCK) void ls_finalize_kernel(
    const float* __restrict__ partial,
    float* __restrict__ out)
{
    const int tid = threadIdx.x;
    float sum = 0.0f;
#pragma unroll
    for (int i = tid; i < LS_ROWS; i += LS_BLOCK)
        sum += partial[i];

#pragma unroll
    for (int off = 32; off >= 1; off >>= 1)
        sum += __shfl_down(sum, off, 64);

    __shared__ float wsum[LS_BLOCK / 64];
    const int lane = tid & 63;
    const int wid  = tid >> 6;
    if (lane == 0) wsum[wid] = sum;
    __syncthreads();

    if (tid == 0)
        out[0] = (wsum[0] + wsum[1]) + (wsum[2] + wsum[3]);  // overwrite: no init needed
}

extern "C" void kernel_launch(void* const* d_in, const int* in_sizes, int n_in,
                              void* d_out, int out_size, void* d_ws, size_t ws_size,
                              hipStream_t stream) {
    const float* x      = (const float*)d_in[0];
    const int*   target = (const int*)d_in[1];
    float*       out    = (float*)d_out;
    float*       ws     = (float*)d_ws;

    const int n_rows = in_sizes[1];          // B*S = 2048

    ls_rowloss_kernel<<<n_rows, LS_BLOCK, 0, stream>>>(x, target, ws);
    ls_finalize_kernel<<<1, LS_BLOCK, 0, stream>>>(ws, out);
}